// Round 6
// baseline (140.238 us; speedup 1.0000x reference)
//
#include <hip/hip_runtime.h>

#define Bn 256
#define Nn 64
#define Tn 50
#define Fn 2
#define En 64
#define Hn 128
#define Rn 30
#define G4 512   // 4*H

typedef _Float16 h2 __attribute__((ext_vector_type(2)));

__device__ __forceinline__ float sigf(float x) {
    return __builtin_amdgcn_rcpf(1.0f + __expf(-x));
}
__device__ __forceinline__ float tanh_fast(float x) {
    return 1.0f - 2.0f * __builtin_amdgcn_rcpf(__expf(2.0f * x) + 1.0f);
}
__device__ __forceinline__ float dot2(h2 a, h2 b, float c) {
#if __has_builtin(__builtin_amdgcn_fdot2)
    return __builtin_amdgcn_fdot2(a, b, c, false);
#else
    return fmaf((float)a[0], (float)b[0], fmaf((float)a[1], (float)b[1], c));
#endif
}
__device__ __forceinline__ h2 pack2(float a, float b) {
    h2 r; r[0] = (_Float16)a; r[1] = (_Float16)b; return r;
}
__device__ __forceinline__ h2 bch2(float u) { return __builtin_bit_cast(h2, u); }

// ---------------- Phase 1: emb[b*T+t, e] = relu(gcn + x@W_res) at node 0 ----------------
__global__ __launch_bounds__(256) void k_emb(const float* __restrict__ src,
                                             const float* __restrict__ W_res,
                                             const float* __restrict__ W_gcn,
                                             const float* __restrict__ b_gcn,
                                             float* __restrict__ emb)
{
    const int wave = threadIdx.x >> 6;
    const int lane = threadIdx.x & 63;
    const int task = blockIdx.x * 4 + wave;      // b*Tn + t
    const int b = task / Tn;
    const int t = task - b * Tn;

    __shared__ float2 xs[4][Nn];

    const float2 xv = *reinterpret_cast<const float2*>(
        src + (((size_t)b * Nn + lane) * Tn + t) * Fn);
    const float x0 = xv.x, x1 = xv.y;
    xs[wave][lane] = xv;
    __syncthreads();

    float rowsum = 0.0f, w0 = 0.0f;
    #pragma unroll
    for (int k = 0; k < Nn; k++) {
        const float2 o = xs[wave][k];
        const float dx = x0 - o.x, dy = x1 - o.y;
        const float w = fminf(__builtin_amdgcn_rsqf(dx * dx + dy * dy), 1.0f);
        rowsum += w;
        if (k == 0) w0 = w;
    }
    const float dinv  = __builtin_amdgcn_rsqf(rowsum);
    const float dinv0 = __shfl(dinv, 0);
    const float a = w0 * dinv0 * dinv;    // A[0, j]

    float p0 = a * x0, p1 = a * x1;
    #pragma unroll
    for (int off = 32; off; off >>= 1) {
        p0 += __shfl_xor(p0, off);
        p1 += __shfl_xor(p1, off);
    }
    const float xa = __shfl(x0, 0);
    const float xb = __shfl(x1, 0);

    const float v = p0 * W_gcn[lane] + p1 * W_gcn[En + lane] + b_gcn[lane]
                  + xa * W_res[lane] + xb * W_res[En + lane];
    emb[(size_t)task * En + lane] = fmaxf(v, 0.0f);
}

// ---------------- Phase 2+3: encoder (T) + decoder (R) LSTM ----------------
// 256 threads/block, 1 batch element/block. Thread t = (cell j=t>>1, pair
// p=t&1). p=0 owns gate cols {j, 128+j} (i,f); p=1 owns {256+j, 384+j} (g,o).
// Each thread holds the FULL 192-deep weight columns as 192 packed h2 VGPRs:
// at 256 threads the backend's budget is 256 VGPRs (empirical law
// budget=65536/blockDim across R1-R5), so no AGPR demotion / scratch.
// No k-split -> no butterfly reduce; one shfl_xor(.,1) pair exchanges the
// partner's gates; both pair threads compute c,h redundantly.
__global__ __launch_bounds__(256) void k_seq(
    const float* __restrict__ emb,
    const float* __restrict__ src,
    const float* __restrict__ W_ih_e, const float* __restrict__ W_hh_e, const float* __restrict__ b_e,
    const float* __restrict__ W1,     const float* __restrict__ b1,
    const float* __restrict__ W_ih_d, const float* __restrict__ W_hh_d, const float* __restrict__ b_d,
    const float* __restrict__ W2,     const float* __restrict__ b2,
    float* __restrict__ out)
{
    const int tid  = threadIdx.x;          // 0..255
    const int lane = tid & 63;
    const int wv   = tid >> 6;             // 0..3
    const int j    = tid >> 1;             // cell 0..127
    const int p    = tid & 1;              // gate-pair selector
    const int b    = blockIdx.x;

    // vbuf: packed fp16 activations; dwords [0,32) = x (64 vals), [32,96) = h (128 vals)
    __shared__ __align__(16) h2 vbuf[2][96];
    __shared__ __align__(8) float red[4][2];

    h2 w[192];        // [0,96): col0 = p*256+j ; [96,192): col1 = p*256+128+j
    float bias0, bias1;
    float c = 0.0f;

    // ---- encoder weights -> packed h2 VGPRs ----
    {
        const int col0 = (p << 8) + j;
        const int col1 = col0 + 128;
        #pragma unroll
        for (int i = 0; i < 96; i++) {
            const int k = 2 * i;          // pairs never straddle the x/h boundary (64 even)
            const float* q0 = (k < En) ? (W_ih_e + (size_t)k * G4 + col0)
                                       : (W_hh_e + (size_t)(k - En) * G4 + col0);
            const float* q1 = (k < En) ? (W_ih_e + (size_t)k * G4 + col1)
                                       : (W_hh_e + (size_t)(k - En) * G4 + col1);
            unsigned int u0 = __builtin_bit_cast(unsigned int, pack2(q0[0], q0[G4]));
            unsigned int u1 = __builtin_bit_cast(unsigned int, pack2(q1[0], q1[G4]));
            asm volatile("" : "+v"(u0), "+v"(u1));
            w[i]      = __builtin_bit_cast(h2, u0);
            w[96 + i] = __builtin_bit_cast(h2, u1);
        }
        bias0 = b_e[col0];
        bias1 = b_e[col1];
    }

    const float* emb_b = emb + (size_t)b * Tn * En;

    // init vbuf[0]: x = emb row 0 (packed), h = 0
    if (tid < 32) {
        const float2 e = *reinterpret_cast<const float2*>(emb_b + 2 * tid);
        vbuf[0][tid] = pack2(e.x, e.y);
    } else if (tid < 96) {
        vbuf[0][tid] = pack2(0.0f, 0.0f);
    }
    __syncthreads();

    // ---- encoder: 50 steps, 1 barrier/step ----
    #pragma unroll 1
    for (int t = 0; t < Tn; t++) {
        const int cur = t & 1;
        float2 xnext;
        const bool pf = (tid < 32) && (t + 1 < Tn);
        if (pf) xnext = *reinterpret_cast<const float2*>(emb_b + (t + 1) * En + 2 * tid);

        const float4* v4 = reinterpret_cast<const float4*>(&vbuf[cur][0]);  // broadcast reads
        float a0 = 0.f, a1 = 0.f, a2 = 0.f, a3 = 0.f;
        #pragma unroll
        for (int i = 0; i < 24; i++) {
            const float4 u = v4[i];
            const h2 q0 = bch2(u.x), q1 = bch2(u.y), q2 = bch2(u.z), q3 = bch2(u.w);
            a0 = dot2(w[4*i+0], q0, a0); a0 = dot2(w[4*i+2], q2, a0);
            a1 = dot2(w[4*i+1], q1, a1); a1 = dot2(w[4*i+3], q3, a1);
            a2 = dot2(w[96+4*i+0], q0, a2); a2 = dot2(w[96+4*i+2], q2, a2);
            a3 = dot2(w[96+4*i+1], q1, a3); a3 = dot2(w[96+4*i+3], q3, a3);
        }
        const float ga = a0 + a1 + bias0;     // p=0: gate i ; p=1: gate g
        const float gb = a2 + a3 + bias1;     // p=0: gate f ; p=1: gate o
        const float gc = __shfl_xor(ga, 1);
        const float gd = __shfl_xor(gb, 1);
        const float gi = p ? gc : ga;
        const float gf = p ? gd : gb;
        const float gg = p ? ga : gc;
        const float go = p ? gb : gd;
        c = sigf(gf) * c + sigf(gi) * tanh_fast(gg);
        const float h = sigf(go) * tanh_fast(c);

        if (p == 0) reinterpret_cast<_Float16*>(&vbuf[cur ^ 1][32])[j] = (_Float16)h;
        if (pf) vbuf[cur ^ 1][tid] = pack2(xnext.x, xnext.y);
        __syncthreads();
    }

    // ---- decoder weights -> same VGPRs ----
    {
        const int col0 = (p << 8) + j;
        const int col1 = col0 + 128;
        #pragma unroll
        for (int i = 0; i < 96; i++) {
            const int k = 2 * i;
            const float* q0 = (k < En) ? (W_ih_d + (size_t)k * G4 + col0)
                                       : (W_hh_d + (size_t)(k - En) * G4 + col0);
            const float* q1 = (k < En) ? (W_ih_d + (size_t)k * G4 + col1)
                                       : (W_hh_d + (size_t)(k - En) * G4 + col1);
            unsigned int u0 = __builtin_bit_cast(unsigned int, pack2(q0[0], q0[G4]));
            unsigned int u1 = __builtin_bit_cast(unsigned int, pack2(q1[0], q1[G4]));
            asm volatile("" : "+v"(u0), "+v"(u1));
            w[i]      = __builtin_bit_cast(h2, u0);
            w[96 + i] = __builtin_bit_cast(h2, u1);
        }
        bias0 = b_d[col0];
        bias1 = b_d[col1];
    }

    float w1a = 0.f, w1b = 0.f, b1v = 0.f;
    if (tid < En) { w1a = W1[tid]; w1b = W1[En + tid]; b1v = b1[tid]; }
    const float w2a = W2[2 * j], w2b = W2[2 * j + 1];
    const float b20 = b2[0], b21 = b2[1];

    // prologue: ed = relu(xin @ W1 + b1), xin = src[b, node 0, T-1, :]
    {
        const float xin0 = src[(size_t)b * Nn * Tn * Fn + (Tn - 1) * Fn + 0];
        const float xin1 = src[(size_t)b * Nn * Tn * Fn + (Tn - 1) * Fn + 1];
        if (tid < En) {                    // whole wave 0 -> shfl safe
            const float e  = fmaxf(xin0 * w1a + xin1 * w1b + b1v, 0.0f);
            const float ep = __shfl_xor(e, 1);
            if (!(tid & 1)) vbuf[0][tid >> 1] = pack2(e, ep);
        }
    }
    __syncthreads();

    // ---- decoder: 30 steps, 2 barriers/step ----
    #pragma unroll 1
    for (int r = 0; r < Rn; r++) {
        const int cur = r & 1;
        const float4* v4 = reinterpret_cast<const float4*>(&vbuf[cur][0]);
        float a0 = 0.f, a1 = 0.f, a2 = 0.f, a3 = 0.f;
        #pragma unroll
        for (int i = 0; i < 24; i++) {
            const float4 u = v4[i];
            const h2 q0 = bch2(u.x), q1 = bch2(u.y), q2 = bch2(u.z), q3 = bch2(u.w);
            a0 = dot2(w[4*i+0], q0, a0); a0 = dot2(w[4*i+2], q2, a0);
            a1 = dot2(w[4*i+1], q1, a1); a1 = dot2(w[4*i+3], q3, a1);
            a2 = dot2(w[96+4*i+0], q0, a2); a2 = dot2(w[96+4*i+2], q2, a2);
            a3 = dot2(w[96+4*i+1], q1, a3); a3 = dot2(w[96+4*i+3], q3, a3);
        }
        const float ga = a0 + a1 + bias0;
        const float gb = a2 + a3 + bias1;
        const float gc = __shfl_xor(ga, 1);
        const float gd = __shfl_xor(gb, 1);
        const float gi = p ? gc : ga;
        const float gf = p ? gd : gb;
        const float gg = p ? ga : gc;
        const float go = p ? gb : gd;
        c = sigf(gf) * c + sigf(gi) * tanh_fast(gg);
        const float h = sigf(go) * tanh_fast(c);

        if (p == 0) reinterpret_cast<_Float16*>(&vbuf[cur ^ 1][32])[j] = (_Float16)h;

        // out = h @ W2 + b2 : p==0 lanes contribute; butterfly over the wave
        float p0 = (p == 0) ? h * w2a : 0.0f;
        float p1 = (p == 0) ? h * w2b : 0.0f;
        #pragma unroll
        for (int off = 32; off; off >>= 1) {
            p0 += __shfl_xor(p0, off);
            p1 += __shfl_xor(p1, off);
        }
        if (lane == 0) { red[wv][0] = p0; red[wv][1] = p1; }
        __syncthreads();

        if (tid < En) {                    // wave 0: finalize out + next ed
            float o0 = b20, o1 = b21;
            #pragma unroll
            for (int k2 = 0; k2 < 4; k2++) { o0 += red[k2][0]; o1 += red[k2][1]; }
            if (tid == 0)
                *reinterpret_cast<float2*>(&out[((size_t)b * Rn + r) * Fn]) = make_float2(o0, o1);
            if (r + 1 < Rn) {
                const float e  = fmaxf(o0 * w1a + o1 * w1b + b1v, 0.0f);
                const float ep = __shfl_xor(e, 1);
                if (!(tid & 1)) vbuf[cur ^ 1][tid >> 1] = pack2(e, ep);
            }
        }
        __syncthreads();
    }
}

extern "C" void kernel_launch(void* const* d_in, const int* in_sizes, int n_in,
                              void* d_out, int out_size, void* d_ws, size_t ws_size,
                              hipStream_t stream)
{
    const float* src    = (const float*)d_in[0];
    const float* W_res  = (const float*)d_in[2];
    const float* W_gcn  = (const float*)d_in[3];
    const float* b_gcn  = (const float*)d_in[4];
    const float* W_ih_e = (const float*)d_in[5];
    const float* W_hh_e = (const float*)d_in[6];
    const float* b_e    = (const float*)d_in[7];
    const float* W1     = (const float*)d_in[8];
    const float* b1     = (const float*)d_in[9];
    const float* W_ih_d = (const float*)d_in[10];
    const float* W_hh_d = (const float*)d_in[11];
    const float* b_d    = (const float*)d_in[12];
    const float* W2     = (const float*)d_in[13];
    const float* b2     = (const float*)d_in[14];

    float* out = (float*)d_out;
    float* emb = (float*)d_ws;   // Bn*Tn*En floats = 3.28 MB scratch

    k_emb<<<(Bn * Tn) / 4, 256, 0, stream>>>(src, W_res, W_gcn, b_gcn, emb);
    k_seq<<<Bn, 256, 0, stream>>>(emb, src,
                                  W_ih_e, W_hh_e, b_e,
                                  W1, b1,
                                  W_ih_d, W_hh_d, b_d,
                                  W2, b2, out);
}

// Round 7
// 129.760 us; speedup vs baseline: 1.0807x; 1.0807x over previous
//
#include <hip/hip_runtime.h>

#define Bn 256
#define Nn 64
#define Tn 50
#define Fn 2
#define En 64
#define Hn 128
#define Rn 30
#define G4 512   // 4*H

typedef _Float16 h2 __attribute__((ext_vector_type(2)));

__device__ __forceinline__ float sigf(float x) {
    return __builtin_amdgcn_rcpf(1.0f + __expf(-x));
}
__device__ __forceinline__ float tanh_fast(float x) {
    return 1.0f - 2.0f * __builtin_amdgcn_rcpf(__expf(2.0f * x) + 1.0f);
}
__device__ __forceinline__ float dot2(h2 a, h2 b, float c) {
#if __has_builtin(__builtin_amdgcn_fdot2)
    return __builtin_amdgcn_fdot2(a, b, c, false);
#else
    return fmaf((float)a[0], (float)b[0], fmaf((float)a[1], (float)b[1], c));
#endif
}
__device__ __forceinline__ h2 pack2(float a, float b) {
    h2 r; r[0] = (_Float16)a; r[1] = (_Float16)b; return r;
}
__device__ __forceinline__ h2 bch2(float u) { return __builtin_bit_cast(h2, u); }
__device__ __forceinline__ float bcf(h2 u) { return __builtin_bit_cast(float, u); }

// ---------------- k_pre: GCN+emb (node 0) fused with XI = emb @ W_ih_e + b_e ----------------
// 200 blocks x 512 threads; block owns 64 tasks (task = b*Tn+t).
// Phase 1: wave w computes emb rows for its 8 tasks (lane = node).
// Phase 2: thread = gate column; 64 tasks x 32 dot2 from LDS-staged emb (fp16).
__global__ __launch_bounds__(512) void k_pre(const float* __restrict__ src,
                                             const float* __restrict__ W_res,
                                             const float* __restrict__ W_gcn,
                                             const float* __restrict__ b_gcn,
                                             const float* __restrict__ W_ih_e,
                                             const float* __restrict__ b_e,
                                             _Float16* __restrict__ XI)
{
    const int tid  = threadIdx.x;
    const int lane = tid & 63;
    const int wv   = tid >> 6;
    const int task0 = blockIdx.x * 64;

    __shared__ __align__(16) _Float16 elds[64][64];   // 8 KB fp16 emb tile
    __shared__ float2 xs[8][Nn];                      // 4 KB per-wave x staging

    // hoisted per-lane weights for the emb epilogue
    const float wg0 = W_gcn[lane], wg1 = W_gcn[En + lane];
    const float wr0 = W_res[lane], wr1 = W_res[En + lane];
    const float bg  = b_gcn[lane];

    // ---- phase 1: 8 tasks per wave ----
    for (int it = 0; it < 8; it++) {
        const int task = task0 + (wv << 3) + it;
        const int b = task / Tn;
        const int t = task - b * Tn;

        const float2 xv = *reinterpret_cast<const float2*>(
            src + (((size_t)b * Nn + lane) * Tn + t) * Fn);
        const float x0 = xv.x, x1 = xv.y;
        xs[wv][lane] = xv;

        // w[j,k] = min(1/dist,1); rsq(0)=+inf handles both clamp and diagonal
        float rowsum = 0.0f, w0 = 0.0f;
        #pragma unroll
        for (int k = 0; k < Nn; k++) {
            const float2 o = xs[wv][k];
            const float dx = x0 - o.x, dy = x1 - o.y;
            const float w = fminf(__builtin_amdgcn_rsqf(dx * dx + dy * dy), 1.0f);
            rowsum += w;
            if (k == 0) w0 = w;
        }
        const float dinv  = __builtin_amdgcn_rsqf(rowsum);
        const float dinv0 = __shfl(dinv, 0);
        const float a = w0 * dinv0 * dinv;    // A[0, lane]

        float p0 = a * x0, p1 = a * x1;
        #pragma unroll
        for (int off = 32; off; off >>= 1) {
            p0 += __shfl_xor(p0, off);
            p1 += __shfl_xor(p1, off);
        }
        const float xa = __shfl(x0, 0);
        const float xb = __shfl(x1, 0);

        const float v = p0 * wg0 + p1 * wg1 + bg + xa * wr0 + xb * wr1;
        elds[(wv << 3) + it][lane] = (_Float16)fmaxf(v, 0.0f);
    }

    // ---- phase 2: XI rows ----
    h2 wih[32];
    #pragma unroll
    for (int q = 0; q < 32; q++)
        wih[q] = pack2(W_ih_e[(size_t)(2 * q) * G4 + tid],
                       W_ih_e[(size_t)(2 * q + 1) * G4 + tid]);
    const float be = b_e[tid];
    __syncthreads();

    for (int it = 0; it < 64; it++) {
        const float4* e4 = reinterpret_cast<const float4*>(&elds[it][0]);
        float acc = be;
        #pragma unroll
        for (int q = 0; q < 8; q++) {
            const float4 u = e4[q];
            acc = dot2(wih[4 * q + 0], bch2(u.x), acc);
            acc = dot2(wih[4 * q + 1], bch2(u.y), acc);
            acc = dot2(wih[4 * q + 2], bch2(u.z), acc);
            acc = dot2(wih[4 * q + 3], bch2(u.w), acc);
        }
        XI[(size_t)(task0 + it) * G4 + tid] = (_Float16)acc;
    }
}

// ---------------- k_seq: encoder (50) + decoder (30) LSTM, weights in LDS ----------------
// 512 threads/block, 1 batch/block, 1 block/CU (128 KB weight LDS).
// Thread = gate column. W_hh fp16 in LDS as [chunk i<16][col 512] 16B chunks
// (8 consecutive k per chunk) -> ds_read_b128 lane-consecutive, conflict-free.
// Encoder x-projection precomputed (XI); decoder W_ih_d (64x512) in registers.
__global__ __launch_bounds__(512) void k_seq(
    const _Float16* __restrict__ XI,
    const float* __restrict__ src,
    const float* __restrict__ W_hh_e,
    const float* __restrict__ W1,     const float* __restrict__ b1,
    const float* __restrict__ W_ih_d, const float* __restrict__ W_hh_d,
    const float* __restrict__ b_d,
    const float* __restrict__ W2,     const float* __restrict__ b2,
    float* __restrict__ out)
{
    const int tid  = threadIdx.x;          // gate column 0..511
    const int lane = tid & 63;
    const int wv   = tid >> 6;
    const int b    = blockIdx.x;

    __shared__ __align__(16) h2 wlds[16 * G4 * 4];    // 128 KB: chunk i, col c at (i*G4+c)*4
    __shared__ float g_lds[G4];                        // 2 KB gates
    __shared__ __align__(16) h2 hbuf[2][Hn / 2];       // packed h
    __shared__ __align__(16) h2 edbuf[2][En / 2];      // packed decoder xt
    __shared__ float red[2][2];

    // ---- stage W_hh_e -> LDS (fp32 global, pack fp16) ----
    #pragma unroll
    for (int i = 0; i < 16; i++) {
        const float* wr = W_hh_e + (size_t)(8 * i) * G4 + tid;
        float4 pk;
        pk.x = bcf(pack2(wr[0],      wr[G4]));
        pk.y = bcf(pack2(wr[2 * G4], wr[3 * G4]));
        pk.z = bcf(pack2(wr[4 * G4], wr[5 * G4]));
        pk.w = bcf(pack2(wr[6 * G4], wr[7 * G4]));
        *reinterpret_cast<float4*>(&wlds[(i * G4 + tid) * 4]) = pk;
    }

    float c = 0.0f;
    if (tid < Hn / 2) hbuf[0][tid] = pack2(0.0f, 0.0f);
    const _Float16* XIrow = XI + (size_t)b * Tn * G4;
    __syncthreads();

    // ---- encoder: 50 steps, 2 barriers/step ----
    #pragma unroll 1
    for (int t = 0; t < Tn; t++) {
        const int cur = t & 1;
        const float xi = (float)XIrow[(size_t)t * G4 + tid];   // issued early, used late

        float acc = 0.0f;
        const float4* hb = reinterpret_cast<const float4*>(&hbuf[cur][0]);
        #pragma unroll
        for (int i = 0; i < 16; i++) {
            const float4 wq = *reinterpret_cast<const float4*>(&wlds[(i * G4 + tid) * 4]);
            const float4 av = hb[i];
            acc = dot2(bch2(wq.x), bch2(av.x), acc);
            acc = dot2(bch2(wq.y), bch2(av.y), acc);
            acc = dot2(bch2(wq.z), bch2(av.z), acc);
            acc = dot2(bch2(wq.w), bch2(av.w), acc);
        }
        g_lds[tid] = acc + xi;
        __syncthreads();

        if (tid < Hn) {
            const float gi = g_lds[tid];
            const float gf = g_lds[Hn + tid];
            const float gg = g_lds[2 * Hn + tid];
            const float go = g_lds[3 * Hn + tid];
            c = sigf(gf) * c + sigf(gi) * tanh_fast(gg);
            const float h = sigf(go) * tanh_fast(c);
            const float hp = __shfl_xor(h, 1);
            if (!(tid & 1)) hbuf[cur ^ 1][tid >> 1] = pack2(h, hp);
        }
        __syncthreads();
    }

    // ---- restage W_hh_d; W_ih_d into registers ----
    #pragma unroll
    for (int i = 0; i < 16; i++) {
        const float* wr = W_hh_d + (size_t)(8 * i) * G4 + tid;
        float4 pk;
        pk.x = bcf(pack2(wr[0],      wr[G4]));
        pk.y = bcf(pack2(wr[2 * G4], wr[3 * G4]));
        pk.z = bcf(pack2(wr[4 * G4], wr[5 * G4]));
        pk.w = bcf(pack2(wr[6 * G4], wr[7 * G4]));
        *reinterpret_cast<float4*>(&wlds[(i * G4 + tid) * 4]) = pk;
    }
    h2 wid[32];
    #pragma unroll
    for (int q = 0; q < 32; q++)
        wid[q] = pack2(W_ih_d[(size_t)(2 * q) * G4 + tid],
                       W_ih_d[(size_t)(2 * q + 1) * G4 + tid]);
    const float bd = b_d[tid];

    float w1a = 0.f, w1b = 0.f, b1v = 0.f;
    if (tid < En) { w1a = W1[tid]; w1b = W1[En + tid]; b1v = b1[tid]; }
    float w2a = 0.f, w2b = 0.f;
    if (tid < Hn) { w2a = W2[2 * tid]; w2b = W2[2 * tid + 1]; }
    const float b20 = b2[0], b21 = b2[1];

    // prologue: ed0 from xin = src[b, node0, T-1, :]
    {
        const float xin0 = src[(size_t)b * Nn * Tn * Fn + (Tn - 1) * Fn + 0];
        const float xin1 = src[(size_t)b * Nn * Tn * Fn + (Tn - 1) * Fn + 1];
        if (tid < En) {
            const float e  = fmaxf(xin0 * w1a + xin1 * w1b + b1v, 0.0f);
            const float ep = __shfl_xor(e, 1);
            if (!(tid & 1)) edbuf[0][tid >> 1] = pack2(e, ep);
        }
    }
    __syncthreads();

    // ---- decoder: 30 steps, 3 barriers/step ----
    #pragma unroll 1
    for (int r = 0; r < Rn; r++) {
        const int cur = r & 1;

        float acc = bd;
        const float4* hb = reinterpret_cast<const float4*>(&hbuf[cur][0]);
        #pragma unroll
        for (int i = 0; i < 16; i++) {
            const float4 wq = *reinterpret_cast<const float4*>(&wlds[(i * G4 + tid) * 4]);
            const float4 av = hb[i];
            acc = dot2(bch2(wq.x), bch2(av.x), acc);
            acc = dot2(bch2(wq.y), bch2(av.y), acc);
            acc = dot2(bch2(wq.z), bch2(av.z), acc);
            acc = dot2(bch2(wq.w), bch2(av.w), acc);
        }
        const float4* ed4 = reinterpret_cast<const float4*>(&edbuf[cur][0]);
        #pragma unroll
        for (int q = 0; q < 8; q++) {
            const float4 u = ed4[q];
            acc = dot2(wid[4 * q + 0], bch2(u.x), acc);
            acc = dot2(wid[4 * q + 1], bch2(u.y), acc);
            acc = dot2(wid[4 * q + 2], bch2(u.z), acc);
            acc = dot2(wid[4 * q + 3], bch2(u.w), acc);
        }
        g_lds[tid] = acc;
        __syncthreads();

        if (tid < Hn) {
            const float gi = g_lds[tid];
            const float gf = g_lds[Hn + tid];
            const float gg = g_lds[2 * Hn + tid];
            const float go = g_lds[3 * Hn + tid];
            c = sigf(gf) * c + sigf(gi) * tanh_fast(gg);
            const float h = sigf(go) * tanh_fast(c);
            const float hp = __shfl_xor(h, 1);
            if (!(tid & 1)) hbuf[cur ^ 1][tid >> 1] = pack2(h, hp);

            float p0 = h * w2a, p1 = h * w2b;
            #pragma unroll
            for (int off = 32; off; off >>= 1) {
                p0 += __shfl_xor(p0, off);
                p1 += __shfl_xor(p1, off);
            }
            if (lane == 0) { red[wv][0] = p0; red[wv][1] = p1; }
        }
        __syncthreads();

        if (tid < En) {
            const float o0 = red[0][0] + red[1][0] + b20;
            const float o1 = red[0][1] + red[1][1] + b21;
            if (tid == 0)
                *reinterpret_cast<float2*>(&out[((size_t)b * Rn + r) * Fn]) = make_float2(o0, o1);
            if (r + 1 < Rn) {
                const float e  = fmaxf(o0 * w1a + o1 * w1b + b1v, 0.0f);
                const float ep = __shfl_xor(e, 1);
                if (!(tid & 1)) edbuf[cur ^ 1][tid >> 1] = pack2(e, ep);
            }
        }
        __syncthreads();
    }
}

extern "C" void kernel_launch(void* const* d_in, const int* in_sizes, int n_in,
                              void* d_out, int out_size, void* d_ws, size_t ws_size,
                              hipStream_t stream)
{
    const float* src    = (const float*)d_in[0];
    const float* W_res  = (const float*)d_in[2];
    const float* W_gcn  = (const float*)d_in[3];
    const float* b_gcn  = (const float*)d_in[4];
    const float* W_ih_e = (const float*)d_in[5];
    const float* W_hh_e = (const float*)d_in[6];
    const float* b_e    = (const float*)d_in[7];
    const float* W1     = (const float*)d_in[8];
    const float* b1     = (const float*)d_in[9];
    const float* W_ih_d = (const float*)d_in[10];
    const float* W_hh_d = (const float*)d_in[11];
    const float* b_d    = (const float*)d_in[12];
    const float* W2     = (const float*)d_in[13];
    const float* b2     = (const float*)d_in[14];

    float* out = (float*)d_out;
    _Float16* XI = (_Float16*)d_ws;   // 12800 x 512 fp16 = 13.1 MB scratch

    k_pre<<<(Bn * Tn) / 64, 512, 0, stream>>>(src, W_res, W_gcn, b_gcn, W_ih_e, b_e, XI);
    k_seq<<<Bn, 512, 0, stream>>>(XI, src,
                                  W_hh_e,
                                  W1, b1,
                                  W_ih_d, W_hh_d, b_d,
                                  W2, b2, out);
}